// Round 1
// baseline (328.472 us; speedup 1.0000x reference)
//
#include <hip/hip_runtime.h>
#include <math.h>

// Problem constants (fixed by setup_inputs)
constexpr int B = 32;
constexpr int C = 256;
constexpr int N = 64;
constexpr int S = 64;
constexpr int NPIX = N * N;       // 4096
constexpr int TILES = NPIX / 256; // 16 pixel-tiles per video
constexpr int QBLOCKS = B * TILES; // 512

#define T_V_INV 10.0f
#define T_Q_INV 10.0f
#define NEG_IOU 0.5f

// ---------------------------------------------------------------------------
// K1: normalize sentence features; emit both [s][c] and transposed [c][s]
// ---------------------------------------------------------------------------
__global__ void k_norm_sents(const float* __restrict__ sents,
                             float* __restrict__ sf_norm,
                             float* __restrict__ sf_t) {
  int s = blockIdx.x, c = threadIdx.x; // 256 threads
  __shared__ float wsum[4];
  float v = sents[s * C + c];
  float ss = v * v;
  #pragma unroll
  for (int o = 32; o; o >>= 1) ss += __shfl_xor(ss, o);
  int lane = c & 63, wid = c >> 6;
  if (lane == 0) wsum[wid] = ss;
  __syncthreads();
  float tot = wsum[0] + wsum[1] + wsum[2] + wsum[3];
  float rn = 1.0f / fmaxf(sqrtf(tot), 1e-12f);
  float o = v * rn;
  sf_norm[s * C + c] = o;
  sf_t[c * S + s] = o;
}

// ---------------------------------------------------------------------------
// K2: scatter_idx[s] = video index b owning sentence s (from num_targets)
// ---------------------------------------------------------------------------
__global__ void k_scatter(const int* __restrict__ nt, int* __restrict__ scatter) {
  int s = threadIdx.x; // 64 threads
  int cum = 0, res = 0;
  for (int b = 0; b < B; b++) {
    int nb = nt[b];
    if (s >= cum && s < cum + nb) res = b;
    cum += nb;
  }
  scatter[s] = res;
}

// ---------------------------------------------------------------------------
// K3: top-1 valid proposal (pixel) per sentence, tie -> lowest flat index
// ---------------------------------------------------------------------------
__global__ void k_topk(const float* __restrict__ iou, int* __restrict__ top_pix) {
  int s = blockIdx.x, tid = threadIdx.x; // 256 threads
  __shared__ float bval[256];
  __shared__ int bidx[256];
  float bv = -1.0f;
  int bi = 0x7fffffff;
  for (int pix = tid; pix < NPIX; pix += 256) {
    int r = pix >> 6, c0 = pix & 63;
    if (c0 >= r) { // upper-triangular = valid proposal
      float v = iou[s * NPIX + pix];
      if (v > bv) { bv = v; bi = pix; } // scan order ascending -> ties keep low idx
    }
  }
  bval[tid] = bv; bidx[tid] = bi;
  __syncthreads();
  for (int st = 128; st; st >>= 1) {
    if (tid < st) {
      float ov = bval[tid + st]; int oi = bidx[tid + st];
      if (ov > bval[tid] || (ov == bval[tid] && oi < bidx[tid])) {
        bval[tid] = ov; bidx[tid] = oi;
      }
    }
    __syncthreads();
  }
  if (tid == 0) top_pix[s] = bidx[0];
}

// ---------------------------------------------------------------------------
// K4: inter-video loss per sentence (64x64 score matrix, one block per s)
// ---------------------------------------------------------------------------
__global__ void k_video(const float* __restrict__ V,
                        const float* __restrict__ sf_norm,
                        const int* __restrict__ scatter,
                        const int* __restrict__ top_pix,
                        float* __restrict__ pos_score,
                        float* __restrict__ loss_vid) {
  int s = blockIdx.x, t = threadIdx.x; // 64 threads = 1 wave
  __shared__ float vh[C];
  int b = scatter[s];
  int pix = top_pix[s];
  const float* vp = V + ((size_t)b * C) * NPIX + pix;
  float vloc[4];
  float ss = 0.0f;
  #pragma unroll
  for (int k = 0; k < 4; k++) {
    vloc[k] = vp[(size_t)(t + 64 * k) * NPIX];
    ss = fmaf(vloc[k], vloc[k], ss);
  }
  #pragma unroll
  for (int o = 32; o; o >>= 1) ss += __shfl_xor(ss, o);
  float rn = 1.0f / fmaxf(sqrtf(ss), 1e-12f);
  #pragma unroll
  for (int k = 0; k < 4; k++) vh[t + 64 * k] = vloc[k] * rn;
  __syncthreads();
  const float* sfr = sf_norm + (size_t)t * C;
  float dot = 0.0f;
  for (int c = 0; c < C; c++) dot = fmaf(vh[c], sfr[c], dot);
  if (t == s) pos_score[s] = dot; // inter_video_pos (K=1)
  float pos = __shfl(dot, s);
  float e = (t == s) ? 0.0f : __expf(dot * T_V_INV);
  #pragma unroll
  for (int o = 32; o; o >>= 1) e += __shfl_xor(e, o);
  if (t == 0) {
    float pp = pos * T_V_INV;
    loss_vid[s] = -(pp - logf(__expf(pp) + e));
  }
}

// ---------------------------------------------------------------------------
// K5 (hot): inter-query exp-sums. Lane = pixel, 64 sentence accumulators.
//   score[s] = sf_norm[s] . (V[b,:,pix]/||V[b,:,pix]||)
//   partial[blk][s] = sum over this block's valid pixels of
//                     exp(score*10) * negmask
// ---------------------------------------------------------------------------
__global__ __launch_bounds__(256) void k_query(const float* __restrict__ V,
                                               const float* __restrict__ iou,
                                               const float* __restrict__ sf_t,
                                               const int* __restrict__ scatter,
                                               float* __restrict__ partials) {
  __shared__ int ssc[S];
  __shared__ float part[4][S];
  int tid = threadIdx.x;
  if (tid < S) ssc[tid] = scatter[tid];
  __syncthreads();

  int b = blockIdx.x >> 4;      // video
  int tile = blockIdx.x & 15;   // pixel tile
  int pix = tile * 256 + tid;
  int row = pix >> 6, col = pix & 63;
  bool valid = (col >= row);

  float acc[S];
  #pragma unroll
  for (int s = 0; s < S; s++) acc[s] = 0.0f;

  if (valid) {
    const float* vp = V + ((size_t)b * C) * NPIX + pix;
    float ss = 0.0f;
    for (int c = 0; c < C; c += 8) {
      float v[8];
      #pragma unroll
      for (int k = 0; k < 8; k++) v[k] = vp[(size_t)(c + k) * NPIX];
      #pragma unroll
      for (int k = 0; k < 8; k++) {
        ss = fmaf(v[k], v[k], ss);
        const float* sfc = sf_t + (c + k) * S; // wave-uniform address
        #pragma unroll
        for (int s = 0; s < S; s++) acc[s] = fmaf(sfc[s], v[k], acc[s]);
      }
    }
    float rn = 1.0f / fmaxf(sqrtf(ss), 1e-12f);
    float sc = rn * T_Q_INV;
    #pragma unroll
    for (int s = 0; s < S; s++) acc[s] = __expf(acc[s] * sc);
    // knock out positives: only sentences owned by this video can be positive
    #pragma unroll
    for (int s = 0; s < S; s++) {
      if (ssc[s] == b) { // uniform branch — only ~2 of 64 taken
        if (iou[s * NPIX + pix] > NEG_IOU) acc[s] = 0.0f;
      }
    }
  }

  // block reduction: 64 per-sentence sums
  int lane = tid & 63, wid = tid >> 6;
  #pragma unroll
  for (int s = 0; s < S; s++) {
    float r = acc[s];
    #pragma unroll
    for (int o = 32; o; o >>= 1) r += __shfl_xor(r, o);
    if (lane == 0) part[wid][s] = r;
  }
  __syncthreads();
  if (tid < S) {
    partials[(size_t)blockIdx.x * S + tid] =
        part[0][tid] + part[1][tid] + part[2][tid] + part[3][tid];
  }
}

// ---------------------------------------------------------------------------
// K6: final reduction -> d_out[0] = loss_inter_video, d_out[1] = loss_inter_query
// ---------------------------------------------------------------------------
__global__ void k_final(const float* __restrict__ partials,
                        const float* __restrict__ pos_score,
                        const float* __restrict__ loss_vid,
                        float* __restrict__ out) {
  int tid = threadIdx.x; // 64 threads = 1 wave
  float ns = 0.0f;
  for (int blk = 0; blk < QBLOCKS; blk++) ns += partials[(size_t)blk * S + tid];
  float p = pos_score[tid] * T_Q_INV;
  float lq = -(p - logf(__expf(p) + ns));
  float lv = loss_vid[tid];
  #pragma unroll
  for (int o = 32; o; o >>= 1) {
    lq += __shfl_xor(lq, o);
    lv += __shfl_xor(lv, o);
  }
  if (tid == 0) {
    out[0] = lv / (float)S;
    out[1] = lq / (float)S;
  }
}

// ---------------------------------------------------------------------------
extern "C" void kernel_launch(void* const* d_in, const int* in_sizes, int n_in,
                              void* d_out, int out_size, void* d_ws, size_t ws_size,
                              hipStream_t stream) {
  const float* V     = (const float*)d_in[0]; // [B,C,N,N]
  const float* sents = (const float*)d_in[1]; // [S,C]
  const int*   nt    = (const int*)d_in[2];   // [B]
  const float* iou   = (const float*)d_in[3]; // [S,N,N]
  // d_in[4] = mask2d: structural triu(N,N) — resolved statically (as in reference)

  float* ws        = (float*)d_ws;
  float* sf_norm   = ws;                       // S*C
  float* sf_t      = ws + S * C;               // C*S
  int*   scatter   = (int*)(ws + 2 * S * C);   // S
  int*   top_pix   = scatter + S;              // S
  float* pos_score = (float*)(top_pix + S);    // S
  float* loss_vid  = pos_score + S;            // S
  float* partials  = loss_vid + S;             // QBLOCKS*S

  k_norm_sents<<<S, 256, 0, stream>>>(sents, sf_norm, sf_t);
  k_scatter<<<1, 64, 0, stream>>>(nt, scatter);
  k_topk<<<S, 256, 0, stream>>>(iou, top_pix);
  k_video<<<S, 64, 0, stream>>>(V, sf_norm, scatter, top_pix, pos_score, loss_vid);
  k_query<<<QBLOCKS, 256, 0, stream>>>(V, iou, sf_t, scatter, partials);
  k_final<<<1, 64, 0, stream>>>(partials, pos_score, loss_vid, (float*)d_out);
}

// Round 2
// 238.176 us; speedup vs baseline: 1.3791x; 1.3791x over previous
//
#include <hip/hip_runtime.h>
#include <hip/hip_bf16.h>
#include <math.h>

// Problem constants (fixed by setup_inputs)
constexpr int B_ = 32;
constexpr int C_ = 256;
constexpr int N_ = 64;
constexpr int S_ = 64;
constexpr int NPIX = N_ * N_;     // 4096
constexpr int QB = B_ * N_;       // 2048 blocks for k_query: (video, row)

#define T_V_INV 10.0f
#define T_Q_INV 10.0f
#define NEG_IOU 0.5f

typedef __attribute__((ext_vector_type(8))) short short8;
typedef __attribute__((ext_vector_type(4))) float f32x4;

static __device__ __forceinline__ unsigned short f2bf(float x) {
  __hip_bfloat16 h = __float2bfloat16(x);
  unsigned short u;
  __builtin_memcpy(&u, &h, sizeof(u));
  return u;
}

// ---------------------------------------------------------------------------
// K1: normalize sentence feats; emit fp32 transposed [c][s] (for k_video) and
//     bf16 MFMA A-fragments: A[m=s][k=c], lane layout m=lane&15, k=quad*8+j.
// ---------------------------------------------------------------------------
__global__ void k_prep(const float* __restrict__ sents,
                       float* __restrict__ sf_t,
                       unsigned short* __restrict__ sf_frag) {
  int s = blockIdx.x, c = threadIdx.x; // 64 x 256
  __shared__ float wsum[4];
  float v = sents[s * C_ + c];
  float ss = v * v;
  #pragma unroll
  for (int o = 32; o; o >>= 1) ss += __shfl_xor(ss, o);
  if ((c & 63) == 0) wsum[c >> 6] = ss;
  __syncthreads();
  float tot = wsum[0] + wsum[1] + wsum[2] + wsum[3];
  float rn = 1.0f / fmaxf(sqrtf(tot), 1e-12f);
  float o = v * rn;
  sf_t[c * S_ + s] = o;
  int ks = c >> 5, q = (c >> 3) & 3, j = c & 7;
  int mt = s >> 4, m = s & 15;
  int lane = q * 16 + m;
  sf_frag[((ks * 4 + mt) * 64 + lane) * 8 + j] = f2bf(o);
}

// ---------------------------------------------------------------------------
// K2: scatter_idx[s] = owning video b
// ---------------------------------------------------------------------------
__global__ void k_scatter(const int* __restrict__ nt, int* __restrict__ scatter) {
  int s = threadIdx.x; // 64 threads
  int cum = 0, res = 0;
  for (int b = 0; b < B_; b++) {
    int nb = nt[b];
    if (s >= cum && s < cum + nb) res = b;
    cum += nb;
  }
  scatter[s] = res;
}

// ---------------------------------------------------------------------------
// K3: top-1 valid pixel per sentence (ties -> lowest flat index)
// ---------------------------------------------------------------------------
__global__ void k_topk(const float* __restrict__ iou, int* __restrict__ top_pix) {
  int s = blockIdx.x, tid = threadIdx.x; // 64 x 256
  __shared__ float bval[256];
  __shared__ int bidx[256];
  float bv = -1.0f;
  int bi = 0x7fffffff;
  for (int pix = tid; pix < NPIX; pix += 256) {
    int r = pix >> 6, c0 = pix & 63;
    if (c0 >= r) {
      float v = iou[s * NPIX + pix];
      if (v > bv) { bv = v; bi = pix; }
    }
  }
  bval[tid] = bv; bidx[tid] = bi;
  __syncthreads();
  for (int st = 128; st; st >>= 1) {
    if (tid < st) {
      float ov = bval[tid + st]; int oi = bidx[tid + st];
      if (ov > bval[tid] || (ov == bval[tid] && oi < bidx[tid])) {
        bval[tid] = ov; bidx[tid] = oi;
      }
    }
    __syncthreads();
  }
  if (tid == 0) top_pix[s] = bidx[0];
}

// ---------------------------------------------------------------------------
// K4: inter-video loss per sentence. sf_t reads are lane-coalesced now.
// ---------------------------------------------------------------------------
__global__ void k_video(const float* __restrict__ V,
                        const float* __restrict__ sf_t,
                        const int* __restrict__ scatter,
                        const int* __restrict__ top_pix,
                        float* __restrict__ pos_score,
                        float* __restrict__ loss_vid) {
  int s = blockIdx.x, t = threadIdx.x; // 64 x 64 (1 wave)
  __shared__ float vh[C_];
  int b = scatter[s];
  int pix = top_pix[s];
  const float* vp = V + ((size_t)b * C_) * NPIX + pix;
  float vloc[4];
  float ss = 0.0f;
  #pragma unroll
  for (int k = 0; k < 4; k++) {
    vloc[k] = vp[(size_t)(t + 64 * k) * NPIX];
    ss = fmaf(vloc[k], vloc[k], ss);
  }
  #pragma unroll
  for (int o = 32; o; o >>= 1) ss += __shfl_xor(ss, o);
  float rn = 1.0f / fmaxf(sqrtf(ss), 1e-12f);
  #pragma unroll
  for (int k = 0; k < 4; k++) vh[t + 64 * k] = vloc[k] * rn;
  __syncthreads();
  float dot = 0.0f;
  #pragma unroll 8
  for (int c = 0; c < C_; c++) dot = fmaf(vh[c], sf_t[c * S_ + t], dot);
  if (t == s) pos_score[s] = dot;
  float pos = __shfl(dot, s);
  float e = (t == s) ? 0.0f : __expf(dot * T_V_INV);
  #pragma unroll
  for (int o = 32; o; o >>= 1) e += __shfl_xor(e, o);
  if (t == 0) {
    float pp = pos * T_V_INV;
    loss_vid[s] = -(pp - logf(__expf(pp) + e));
  }
}

// ---------------------------------------------------------------------------
// K5 (hot): MFMA bf16 score GEMM + fused normalize/exp/mask/partial-reduce.
//   Block = (video b, row r). Wave w covers cols [w*16, w*16+16).
//   Per wave: D[64 sents][16 pix] via 4 Mtiles of 16x16x32, K-loop over C.
//   B-fragments load straight from global (4x64B lines per instr, no LDS).
// ---------------------------------------------------------------------------
__global__ __launch_bounds__(256) void k_query(
    const float* __restrict__ V, const float* __restrict__ iou,
    const short8* __restrict__ Afrag, const int* __restrict__ scatter,
    float* __restrict__ partials) {
  __shared__ int ssc[S_];
  __shared__ float part[4][S_];
  int tid = threadIdx.x;
  if (tid < S_) ssc[tid] = scatter[tid];
  __syncthreads();

  int b = blockIdx.x >> 6, r = blockIdx.x & 63;
  int w = tid >> 6, lane = tid & 63;
  int n = lane & 15, q = lane >> 4;
  int col = w * 16 + n;
  int pix = r * 64 + col;
  bool active = (col >= r); // triangle mask; inactive lanes contribute zeros

  const float* vb = V + (size_t)b * C_ * NPIX + pix;
  f32x4 acc[4] = {f32x4{0,0,0,0}, f32x4{0,0,0,0}, f32x4{0,0,0,0}, f32x4{0,0,0,0}};
  float ssq = 0.0f;

  for (int ks = 0; ks < 8; ks++) {
    short8 bfrag;
    #pragma unroll
    for (int j = 0; j < 8; j++) {
      int c = ks * 32 + q * 8 + j; // B[k][n]: k=quad*8+j, n=lane&15
      float v = active ? vb[(size_t)c * NPIX] : 0.0f;
      ssq = fmaf(v, v, ssq);
      bfrag[j] = (short)f2bf(v);
    }
    #pragma unroll
    for (int mt = 0; mt < 4; mt++) {
      short8 a = Afrag[(ks * 4 + mt) * 64 + lane];
      acc[mt] = __builtin_amdgcn_mfma_f32_16x16x32_bf16(a, bfrag, acc[mt], 0, 0, 0);
    }
  }

  // ssq holds this quad's c-subset; fold quads -> full sum per pixel
  ssq += __shfl_xor(ssq, 16);
  ssq += __shfl_xor(ssq, 32);
  float rs = T_Q_INV / fmaxf(sqrtf(ssq), 1e-12f);

  // Epilogue: D layout col(pix)=lane&15, row(sent)=quad*4+rr
  #pragma unroll
  for (int mt = 0; mt < 4; mt++) {
    #pragma unroll
    for (int rr = 0; rr < 4; rr++) {
      int s = mt * 16 + q * 4 + rr;
      float e = active ? __expf(acc[mt][rr] * rs) : 0.0f;
      if (active && ssc[s] == b) {
        if (iou[s * NPIX + pix] > NEG_IOU) e = 0.0f; // positive -> not a negative
      }
      e += __shfl_xor(e, 1);
      e += __shfl_xor(e, 2);
      e += __shfl_xor(e, 4);
      e += __shfl_xor(e, 8); // summed over the 16 pixels of this wave
      if (n == 0) part[w][s] = e;
    }
  }
  __syncthreads();
  if (tid < S_) {
    partials[(size_t)blockIdx.x * S_ + tid] =
        part[0][tid] + part[1][tid] + part[2][tid] + part[3][tid];
  }
}

// ---------------------------------------------------------------------------
// K6: per-sentence negative-sum reduction + inter-query loss (64 blocks)
// ---------------------------------------------------------------------------
__global__ void k_loss(const float* __restrict__ partials,
                       const float* __restrict__ pos_score,
                       float* __restrict__ loss_q) {
  int s = blockIdx.x, tid = threadIdx.x; // 64 x 256
  __shared__ float wsum[4];
  float acc = 0.0f;
  for (int blk = tid; blk < QB; blk += 256) acc += partials[(size_t)blk * S_ + s];
  #pragma unroll
  for (int o = 32; o; o >>= 1) acc += __shfl_xor(acc, o);
  if ((tid & 63) == 0) wsum[tid >> 6] = acc;
  __syncthreads();
  if (tid == 0) {
    float neg = wsum[0] + wsum[1] + wsum[2] + wsum[3];
    float p = pos_score[s] * T_Q_INV;
    loss_q[s] = -(p - logf(__expf(p) + neg));
  }
}

// ---------------------------------------------------------------------------
// K7: final means -> out[0], out[1]
// ---------------------------------------------------------------------------
__global__ void k_final(const float* __restrict__ loss_vid,
                        const float* __restrict__ loss_q,
                        float* __restrict__ out) {
  int tid = threadIdx.x; // 64 = 1 wave
  float lv = loss_vid[tid];
  float lq = loss_q[tid];
  #pragma unroll
  for (int o = 32; o; o >>= 1) {
    lv += __shfl_xor(lv, o);
    lq += __shfl_xor(lq, o);
  }
  if (tid == 0) {
    out[0] = lv / (float)S_;
    out[1] = lq / (float)S_;
  }
}

// ---------------------------------------------------------------------------
extern "C" void kernel_launch(void* const* d_in, const int* in_sizes, int n_in,
                              void* d_out, int out_size, void* d_ws, size_t ws_size,
                              hipStream_t stream) {
  const float* V     = (const float*)d_in[0]; // [B,C,N,N]
  const float* sents = (const float*)d_in[1]; // [S,C]
  const int*   nt    = (const int*)d_in[2];   // [B]
  const float* iou   = (const float*)d_in[3]; // [S,N,N]
  // d_in[4] = mask2d: structural triu — resolved statically (as in reference)

  float* ws = (float*)d_ws;
  float*          sf_t    = ws;                         // 16384 floats
  unsigned short* sf_frag = (unsigned short*)(ws + 16384); // 16384 bf16 (8192 floats)
  int*   scatter   = (int*)(ws + 16384 + 8192);
  int*   top_pix   = scatter + S_;
  float* pos_score = (float*)(top_pix + S_);
  float* loss_vid  = pos_score + S_;
  float* loss_q    = loss_vid + S_;
  float* partials  = loss_q + S_;                       // QB*S = 131072 floats

  k_prep   <<<S_, 256, 0, stream>>>(sents, sf_t, sf_frag);
  k_scatter<<<1, 64, 0, stream>>>(nt, scatter);
  k_topk   <<<S_, 256, 0, stream>>>(iou, top_pix);
  k_video  <<<S_, 64, 0, stream>>>(V, sf_t, scatter, top_pix, pos_score, loss_vid);
  k_query  <<<QB, 256, 0, stream>>>(V, iou, (const short8*)sf_frag, scatter, partials);
  k_loss   <<<S_, 256, 0, stream>>>(partials, pos_score, loss_q);
  k_final  <<<1, 64, 0, stream>>>(loss_vid, loss_q, (float*)d_out);
}